// Round 9
// baseline (237.058 us; speedup 1.0000x reference)
//
#include <hip/hip_runtime.h>

typedef __attribute__((ext_vector_type(4))) float floatx4;
typedef __attribute__((ext_vector_type(8))) short shortx8;

// db4 analysis filters, TRUE-convolution orientation:
// y[m] = sum_i F[i] * xp[2m + 7 - i]  (xp reflect-padded, pl = 6 at every level)
__device__ __constant__ float DLO[8] = {
    -0.010597401784997278f, 0.032883011666982945f,
     0.030841381835986965f, -0.18703481171888114f,
    -0.02798376941698385f,  0.6308807679295904f,
     0.7148465705525415f,   0.23037781330885523f};
__device__ __constant__ float DHI[8] = {
    -0.23037781330885523f,  0.7148465705525415f,
    -0.6308807679295904f,  -0.02798376941698385f,
     0.18703481171888114f,  0.030841381835986965f,
     0.032883011666982945f, -0.010597401784997278f};

__device__ __forceinline__ unsigned short f2bf_rne(float f) {
  unsigned u = __builtin_bit_cast(unsigned, f);
  unsigned r = (u + 0x7FFFu + ((u >> 16) & 1u)) >> 16;
  return (unsigned short)r;
}

// One analysis filter-bank level. pl (left reflect pad) == 6 for n in {64,35,21}.
template <int N, int OUT>
__device__ __forceinline__ void afb(const float* x, float* lo, float* hi) {
#pragma unroll
  for (int m = 0; m < OUT; ++m) {
    float aL = 0.f, aH = 0.f;
#pragma unroll
    for (int i = 0; i < 8; ++i) {
      int s = 2 * m + 1 - i;              // 2m + 7 - i - 6
      s = (s < 0) ? -s : s;               // reflect (no edge repeat)
      s = (s >= N) ? (2 * N - 2 - s) : s;
      float v = x[s];
      aL = fmaf(DLO[i], v, aL);
      aH = fmaf(DHI[i], v, aH);
    }
    lo[m] = aL; hi[m] = aH;
  }
}

// Fused M-build + W2-build (verified rounds 2/3/4/6/7).
// grid (64, 4), 256 threads. blockIdx.x = k, blockIdx.y = 16-wide tp slice.
// W2[k][tp*64+hw] = sum_t M[t][tp] * conv_w[k][t][hw], rounded to bf16.
__global__ __launch_bounds__(256) void build_w2_fused(
    const float* __restrict__ cw, unsigned short* __restrict__ W2) {
  __shared__ float Ml[84 * 64];
  __shared__ float Cl[84 * 64];
  const int k = blockIdx.x;
  const int tid = threadIdx.x;

  if (tid < 64) {  // column tid of M = DWT(e_tid)
    const int i = tid;
    float sig[64];
#pragma unroll
    for (int t = 0; t < 64; ++t) sig[t] = (t == i) ? 1.f : 0.f;
    float lo1[35], hi1[35], lo2[21], hi2[21], lo3[14], hi3[14];
    afb<64, 35>(sig, lo1, hi1);
    afb<35, 21>(lo1, lo2, hi2);
    afb<21, 14>(lo2, lo3, hi3);
#pragma unroll
    for (int t = 0; t < 14; ++t) Ml[t * 64 + i] = lo3[t];
#pragma unroll
    for (int t = 0; t < 35; ++t) Ml[(14 + t) * 64 + i] = hi1[t];
#pragma unroll
    for (int t = 0; t < 21; ++t) Ml[(49 + t) * 64 + i] = hi2[t];
#pragma unroll
    for (int t = 0; t < 14; ++t) Ml[(70 + t) * 64 + i] = hi3[t];
  }
  const float* cwk = cw + (size_t)k * (84 * 64);
  for (int idx = tid; idx < 84 * 64; idx += 256) Cl[idx] = cwk[idx];
  __syncthreads();

  const int tp  = blockIdx.y * 16 + (tid >> 4);
  const int hw0 = (tid & 15) * 4;
  float a0 = 0.f, a1 = 0.f, a2 = 0.f, a3 = 0.f;
#pragma unroll 4
  for (int t = 0; t < 84; ++t) {
    const float mv = Ml[t * 64 + tp];
    const float4 cv = *(const float4*)&Cl[t * 64 + hw0];
    a0 = fmaf(mv, cv.x, a0);
    a1 = fmaf(mv, cv.y, a1);
    a2 = fmaf(mv, cv.z, a2);
    a3 = fmaf(mv, cv.w, a3);
  }
  uint2 pk;
  pk.x = (unsigned)f2bf_rne(a0) | ((unsigned)f2bf_rne(a1) << 16);
  pk.y = (unsigned)f2bf_rne(a2) | ((unsigned)f2bf_rne(a3) << 16);
  *(uint2*)(W2 + (size_t)k * 4096 + tp * 64 + hw0) = pk;
}

// Streaming GEMM: out[8192][64] = leaky(A[8192][4096] * W2[64][4096]^T + b)
// Round-0 structure with ONE variable changed: BK 128 -> 256.
// The gemm window carries ~257 MB mixed traffic (84 MB A fetch after L3
// hits + ~171 MB inherited dirty-poison writeback + out) at only ~4.4 TB/s.
// Cache-policy bypasses were null (rounds 6/7), so the writeback stays;
// the remaining lever is mixed-BW utilization: halve the barrier count
// (16 lgkmcnt+barrier pairs instead of 32) and double per-phase in-flight
// bytes (256 B/thread, 128 KB/CU nominal). LDS 99 KB, still 1 block/CU.
#define BM 32
#define BN 64
#define BK 256
#define LDK 264   // +8 bf16 pad: 528 B row stride = 132 dw = 4 mod 32 ->
                  // same 2-way bank-alias class as the proven LDK=136
#define NITER 16  // 4096 / BK

__global__ __launch_bounds__(512) void gemm_kernel(
    const float* __restrict__ A, const unsigned short* __restrict__ W2,
    const float* __restrict__ bias, float* __restrict__ out) {
  __shared__ alignas(16) short As[2][BM * LDK];   // 33792 B
  __shared__ alignas(16) short Bs[2][BN * LDK];   // 67584 B (total 99 KB)

  const int tid = threadIdx.x;
  const int b0 = blockIdx.x * BM;

  // staging maps: 512 threads cover 32x256 fp32 A (16 floats/thread) and
  // 64x256 bf16 B (32 bf16/thread)
  const int ar = tid >> 4;             // 0..31  (A row in tile)
  const int ac = (tid & 15) * 16;      // 0..240 (16 floats)
  const int bn = tid >> 3;             // 0..63  (W2 row)
  const int bc = (tid & 7) * 32;       // 0..224 (32 bf16)

  const float* aptr = A + (size_t)(b0 + ar) * 4096 + ac;
  const unsigned short* bptr = W2 + (size_t)bn * 4096 + bc;

  // mfma tile assignment: 8 waves -> 2 mtiles x 4 ntiles of 16x16
  const int lane = tid & 63;
  const int wave = tid >> 6;
  const int mt = wave >> 2;
  const int nt = wave & 3;
  const int frow = lane & 15;
  const int fk = (lane >> 4) * 8;

  floatx4 acc = {0.f, 0.f, 0.f, 0.f};

  // depth-2 register prefetch (chunks 0 and 1); A loads hinted nt
  floatx4 aA_0[4], aA_1[4];
  uint4   bq_0[4], bq_1[4];
#pragma unroll
  for (int j = 0; j < 4; ++j) {
    aA_0[j] = __builtin_nontemporal_load((const floatx4*)(aptr + j * 4));
    bq_0[j] = *(const uint4*)(bptr + j * 8);
    aA_1[j] = __builtin_nontemporal_load((const floatx4*)(aptr + BK + j * 4));
    bq_1[j] = *(const uint4*)(bptr + BK + j * 8);
  }

  // Raw barrier: lgkmcnt(0) orders LDS writes, but vmcnt is NOT drained, so
  // the depth-2 global prefetches stay in flight across the barrier.
#define GSTEP(S, I)                                                          \
  do {                                                                       \
    shortx8 av0, av1;                                                        \
    av0[0] = (short)f2bf_rne(aA_##S[0][0]); av0[1] = (short)f2bf_rne(aA_##S[0][1]); \
    av0[2] = (short)f2bf_rne(aA_##S[0][2]); av0[3] = (short)f2bf_rne(aA_##S[0][3]); \
    av0[4] = (short)f2bf_rne(aA_##S[1][0]); av0[5] = (short)f2bf_rne(aA_##S[1][1]); \
    av0[6] = (short)f2bf_rne(aA_##S[1][2]); av0[7] = (short)f2bf_rne(aA_##S[1][3]); \
    av1[0] = (short)f2bf_rne(aA_##S[2][0]); av1[1] = (short)f2bf_rne(aA_##S[2][1]); \
    av1[2] = (short)f2bf_rne(aA_##S[2][2]); av1[3] = (short)f2bf_rne(aA_##S[2][3]); \
    av1[4] = (short)f2bf_rne(aA_##S[3][0]); av1[5] = (short)f2bf_rne(aA_##S[3][1]); \
    av1[6] = (short)f2bf_rne(aA_##S[3][2]); av1[7] = (short)f2bf_rne(aA_##S[3][3]); \
    *(shortx8*)&As[S][ar * LDK + ac] = av0;                                  \
    *(shortx8*)&As[S][ar * LDK + ac + 8] = av1;                              \
    *(uint4*)&Bs[S][bn * LDK + bc] = bq_##S[0];                              \
    *(uint4*)&Bs[S][bn * LDK + bc + 8] = bq_##S[1];                          \
    *(uint4*)&Bs[S][bn * LDK + bc + 16] = bq_##S[2];                         \
    *(uint4*)&Bs[S][bn * LDK + bc + 24] = bq_##S[3];                         \
    __asm__ __volatile__("s_waitcnt lgkmcnt(0)\n\ts_barrier" ::: "memory");  \
    if ((I) + 2 < NITER) {                                                   \
      const int c2 = ((I) + 2) * BK;                                         \
      _Pragma("unroll")                                                      \
      for (int j = 0; j < 4; ++j) {                                          \
        aA_##S[j] = __builtin_nontemporal_load(                              \
            (const floatx4*)(aptr + c2 + j * 4));                            \
        bq_##S[j] = *(const uint4*)(bptr + c2 + j * 8);                      \
      }                                                                      \
    }                                                                        \
    _Pragma("unroll")                                                        \
    for (int kk = 0; kk < 8; ++kk) {                                         \
      shortx8 af = *(const shortx8*)&As[S][(mt * 16 + frow) * LDK + kk * 32 + fk]; \
      shortx8 bf = *(const shortx8*)&Bs[S][(nt * 16 + frow) * LDK + kk * 32 + fk]; \
      acc = __builtin_amdgcn_mfma_f32_16x16x32_bf16(af, bf, acc, 0, 0, 0);   \
    }                                                                        \
  } while (0)

  for (int i = 0; i < NITER; i += 2) {
    GSTEP(0, i);
    GSTEP(1, i + 1);
  }
#undef GSTEP

  // epilogue: D layout col = lane&15 (n), row = (lane>>4)*4 + r (m)
  const int ocol = nt * 16 + (lane & 15);
  const int orow0 = b0 + mt * 16 + (lane >> 4) * 4;
  const float bv = bias[ocol];
#pragma unroll
  for (int r = 0; r < 4; ++r) {
    float v = acc[r] + bv;
    out[(size_t)(orow0 + r) * 64 + ocol] = (v >= 0.f) ? v : 1.0e-3f * v;
  }
}

extern "C" void kernel_launch(void* const* d_in, const int* in_sizes, int n_in,
                              void* d_out, int out_size, void* d_ws, size_t ws_size,
                              hipStream_t stream) {
  const float* x      = (const float*)d_in[0];  // [8192,1,64,8,8]
  const float* conv_w = (const float*)d_in[1];  // [64,84,8,8]
  const float* conv_b = (const float*)d_in[2];  // [64]
  float* out = (float*)d_out;                   // [8192,64]

  unsigned short* W2 = (unsigned short*)d_ws;   // 64*4096 bf16 = 512 KB

  build_w2_fused<<<dim3(64, 4), 256, 0, stream>>>(conv_w, W2);
  gemm_kernel<<<256, 512, 0, stream>>>(x, W2, conv_b, out);
}

// Round 10
// 201.265 us; speedup vs baseline: 1.1778x; 1.1778x over previous
//
#include <hip/hip_runtime.h>

typedef __attribute__((ext_vector_type(4))) float floatx4;
typedef __attribute__((ext_vector_type(8))) short shortx8;

// db4 analysis filters, TRUE-convolution orientation:
// y[m] = sum_i F[i] * xp[2m + 7 - i]  (xp reflect-padded, pl = 6 at every level)
__device__ __constant__ float DLO[8] = {
    -0.010597401784997278f, 0.032883011666982945f,
     0.030841381835986965f, -0.18703481171888114f,
    -0.02798376941698385f,  0.6308807679295904f,
     0.7148465705525415f,   0.23037781330885523f};
__device__ __constant__ float DHI[8] = {
    -0.23037781330885523f,  0.7148465705525415f,
    -0.6308807679295904f,  -0.02798376941698385f,
     0.18703481171888114f,  0.030841381835986965f,
     0.032883011666982945f, -0.010597401784997278f};

__device__ __forceinline__ unsigned short f2bf_rne(float f) {
  unsigned u = __builtin_bit_cast(unsigned, f);
  unsigned r = (u + 0x7FFFu + ((u >> 16) & 1u)) >> 16;
  return (unsigned short)r;
}

// One analysis filter-bank level. pl (left reflect pad) == 6 for n in {64,35,21}.
template <int N, int OUT>
__device__ __forceinline__ void afb(const float* x, float* lo, float* hi) {
#pragma unroll
  for (int m = 0; m < OUT; ++m) {
    float aL = 0.f, aH = 0.f;
#pragma unroll
    for (int i = 0; i < 8; ++i) {
      int s = 2 * m + 1 - i;              // 2m + 7 - i - 6
      s = (s < 0) ? -s : s;               // reflect (no edge repeat)
      s = (s >= N) ? (2 * N - 2 - s) : s;
      float v = x[s];
      aL = fmaf(DLO[i], v, aL);
      aH = fmaf(DHI[i], v, aH);
    }
    lo[m] = aL; hi[m] = aH;
  }
}

// Fused M-build + W2-build (verified rounds 2/3/4/6/7/9).
// grid (64, 4), 256 threads. blockIdx.x = k, blockIdx.y = 16-wide tp slice.
// W2[k][tp*64+hw] = sum_t M[t][tp] * conv_w[k][t][hw], rounded to bf16.
__global__ __launch_bounds__(256) void build_w2_fused(
    const float* __restrict__ cw, unsigned short* __restrict__ W2) {
  __shared__ float Ml[84 * 64];
  __shared__ float Cl[84 * 64];
  const int k = blockIdx.x;
  const int tid = threadIdx.x;

  if (tid < 64) {  // column tid of M = DWT(e_tid)
    const int i = tid;
    float sig[64];
#pragma unroll
    for (int t = 0; t < 64; ++t) sig[t] = (t == i) ? 1.f : 0.f;
    float lo1[35], hi1[35], lo2[21], hi2[21], lo3[14], hi3[14];
    afb<64, 35>(sig, lo1, hi1);
    afb<35, 21>(lo1, lo2, hi2);
    afb<21, 14>(lo2, lo3, hi3);
#pragma unroll
    for (int t = 0; t < 14; ++t) Ml[t * 64 + i] = lo3[t];
#pragma unroll
    for (int t = 0; t < 35; ++t) Ml[(14 + t) * 64 + i] = hi1[t];
#pragma unroll
    for (int t = 0; t < 21; ++t) Ml[(49 + t) * 64 + i] = hi2[t];
#pragma unroll
    for (int t = 0; t < 14; ++t) Ml[(70 + t) * 64 + i] = hi3[t];
  }
  const float* cwk = cw + (size_t)k * (84 * 64);
  for (int idx = tid; idx < 84 * 64; idx += 256) Cl[idx] = cwk[idx];
  __syncthreads();

  const int tp  = blockIdx.y * 16 + (tid >> 4);
  const int hw0 = (tid & 15) * 4;
  float a0 = 0.f, a1 = 0.f, a2 = 0.f, a3 = 0.f;
#pragma unroll 4
  for (int t = 0; t < 84; ++t) {
    const float mv = Ml[t * 64 + tp];
    const float4 cv = *(const float4*)&Cl[t * 64 + hw0];
    a0 = fmaf(mv, cv.x, a0);
    a1 = fmaf(mv, cv.y, a1);
    a2 = fmaf(mv, cv.z, a2);
    a3 = fmaf(mv, cv.w, a3);
  }
  uint2 pk;
  pk.x = (unsigned)f2bf_rne(a0) | ((unsigned)f2bf_rne(a1) << 16);
  pk.y = (unsigned)f2bf_rne(a2) | ((unsigned)f2bf_rne(a3) << 16);
  *(uint2*)(W2 + (size_t)k * 4096 + tp * 64 + hw0) = pk;
}

// Streaming GEMM (round-0 structure + NT A-loads — session best, 201.5 µs):
// out[8192][64] = leaky(A[8192][4096] * W2[64][4096]^T + b).
// Session ledger: 2-blk/CU (+63), barrier-free split-K (+10), B-in-LDS-once
// (+11), BK=256 (+35) all regress; NT / sc0|nt|sc1 cache policies null.
// The gemm window carries ~257 MB mixed traffic (134 MB mandatory A-read +
// ~170 MB inherited dirty-poison writeback from the harness's 512 MiB fill
// + output) at ~4.5-5 TB/s — near the mixed read/write ceiling.
#define BM 32
#define BN 64
#define BK 128
#define LDK 136   // +8 bf16 pad: frag-read row stride 272B -> 2-way bank alias (free)
#define NITER 32  // 4096 / BK

__global__ __launch_bounds__(512) void gemm_kernel(
    const float* __restrict__ A, const unsigned short* __restrict__ W2,
    const float* __restrict__ bias, float* __restrict__ out) {
  __shared__ alignas(16) short As[2][BM * LDK];
  __shared__ alignas(16) short Bs[2][BN * LDK];

  const int tid = threadIdx.x;
  const int b0 = blockIdx.x * BM;

  // staging maps
  const int ar = tid >> 4;             // 0..31  (A row in tile)
  const int ac = (tid & 15) * 8;       // 0..120 (A col in chunk, 8 floats)
  const int bn = tid >> 3;             // 0..63  (W2 row)
  const int bc = (tid & 7) * 16;       // 0..112 (16 bf16)

  const float* aptr = A + (size_t)(b0 + ar) * 4096 + ac;
  const unsigned short* bptr = W2 + (size_t)bn * 4096 + bc;

  // mfma tile assignment: 8 waves -> 2 mtiles x 4 ntiles of 16x16
  const int lane = tid & 63;
  const int wave = tid >> 6;
  const int mt = wave >> 2;
  const int nt = wave & 3;
  const int frow = lane & 15;
  const int fk = (lane >> 4) * 8;

  floatx4 acc = {0.f, 0.f, 0.f, 0.f};

  // depth-2 register prefetch (chunks 0 and 1); A loads hinted nt
  floatx4 a0_0 = __builtin_nontemporal_load((const floatx4*)(aptr + 0));
  floatx4 a1_0 = __builtin_nontemporal_load((const floatx4*)(aptr + 4));
  uint4  b0_0 = *(const uint4*)(bptr + 0);
  uint4  b1_0 = *(const uint4*)(bptr + 8);
  floatx4 a0_1 = __builtin_nontemporal_load((const floatx4*)(aptr + BK));
  floatx4 a1_1 = __builtin_nontemporal_load((const floatx4*)(aptr + BK + 4));
  uint4  b0_1 = *(const uint4*)(bptr + BK);
  uint4  b1_1 = *(const uint4*)(bptr + BK + 8);

  // Raw barrier: lgkmcnt(0) orders LDS writes, but vmcnt is NOT drained, so
  // the depth-2 global prefetches stay in flight across the barrier.
#define GSTEP(S, I)                                                          \
  do {                                                                       \
    shortx8 av;                                                              \
    av[0] = (short)f2bf_rne(a0_##S[0]); av[1] = (short)f2bf_rne(a0_##S[1]);  \
    av[2] = (short)f2bf_rne(a0_##S[2]); av[3] = (short)f2bf_rne(a0_##S[3]);  \
    av[4] = (short)f2bf_rne(a1_##S[0]); av[5] = (short)f2bf_rne(a1_##S[1]);  \
    av[6] = (short)f2bf_rne(a1_##S[2]); av[7] = (short)f2bf_rne(a1_##S[3]);  \
    *(shortx8*)&As[S][ar * LDK + ac] = av;                                   \
    *(uint4*)&Bs[S][bn * LDK + bc] = b0_##S;                                 \
    *(uint4*)&Bs[S][bn * LDK + bc + 8] = b1_##S;                             \
    __asm__ __volatile__("s_waitcnt lgkmcnt(0)\n\ts_barrier" ::: "memory");  \
    if ((I) + 2 < NITER) {                                                   \
      const int c2 = ((I) + 2) * BK;                                         \
      a0_##S = __builtin_nontemporal_load((const floatx4*)(aptr + c2));      \
      a1_##S = __builtin_nontemporal_load((const floatx4*)(aptr + c2 + 4));  \
      b0_##S = *(const uint4*)(bptr + c2);                                   \
      b1_##S = *(const uint4*)(bptr + c2 + 8);                               \
    }                                                                        \
    _Pragma("unroll")                                                        \
    for (int kk = 0; kk < 4; ++kk) {                                         \
      shortx8 af = *(const shortx8*)&As[S][(mt * 16 + frow) * LDK + kk * 32 + fk]; \
      shortx8 bf = *(const shortx8*)&Bs[S][(nt * 16 + frow) * LDK + kk * 32 + fk]; \
      acc = __builtin_amdgcn_mfma_f32_16x16x32_bf16(af, bf, acc, 0, 0, 0);   \
    }                                                                        \
  } while (0)

  for (int i = 0; i < NITER; i += 2) {
    GSTEP(0, i);
    GSTEP(1, i + 1);
  }
#undef GSTEP

  // epilogue: D layout col = lane&15 (n), row = (lane>>4)*4 + r (m)
  const int ocol = nt * 16 + (lane & 15);
  const int orow0 = b0 + mt * 16 + (lane >> 4) * 4;
  const float bv = bias[ocol];
#pragma unroll
  for (int r = 0; r < 4; ++r) {
    float v = acc[r] + bv;
    out[(size_t)(orow0 + r) * 64 + ocol] = (v >= 0.f) ? v : 1.0e-3f * v;
  }
}

extern "C" void kernel_launch(void* const* d_in, const int* in_sizes, int n_in,
                              void* d_out, int out_size, void* d_ws, size_t ws_size,
                              hipStream_t stream) {
  const float* x      = (const float*)d_in[0];  // [8192,1,64,8,8]
  const float* conv_w = (const float*)d_in[1];  // [64,84,8,8]
  const float* conv_b = (const float*)d_in[2];  // [64]
  float* out = (float*)d_out;                   // [8192,64]

  unsigned short* W2 = (unsigned short*)d_ws;   // 64*4096 bf16 = 512 KB

  build_w2_fused<<<dim3(64, 4), 256, 0, stream>>>(conv_w, W2);
  gemm_kernel<<<256, 512, 0, stream>>>(x, W2, conv_b, out);
}